// Round 25
// baseline (201.936 us; speedup 1.0000x reference)
//
#include <hip/hip_runtime.h>
#include <hip/hip_bf16.h>

#define BATCH 64
#define MDIM 512
#define NDIM 1024
#define KDIM 1024

#define BM 256
#define BN 256
#define BK 64
#define NKT (KDIM / BK)     // 16 K-tiles

typedef __attribute__((ext_vector_type(4))) float f32x4;
typedef __attribute__((ext_vector_type(8))) short bf16x8;
typedef __attribute__((ext_vector_type(4))) unsigned int u32x4;

__device__ __forceinline__ unsigned int cvt2(float lo, float hi) {
    __hip_bfloat162 h = __float22bfloat162_rn(float2{lo, hi});
    return *(unsigned int*)&h;
}

#define MFMA16(a, b, c) __builtin_amdgcn_mfma_f32_16x16x32_bf16((a), (b), (c), 0, 0, 0)
#define SB0 __builtin_amdgcn_sched_barrier(0)
#define WAITLG(n) do { asm volatile("s_waitcnt lgkmcnt(" #n ")" ::: "memory"); SB0; } while (0)
#define BAR do { SB0; __builtin_amdgcn_s_barrier(); SB0; } while (0)

// R21 schedule (counted lgkm waits, 4 phases/tile) + persistent pair:
// 256 blocks; block = (batch, tn); computes tm=0 then tm=1 with the
// staging pipeline warm across the pair (W tile identical for both).
__global__ __launch_bounds__(512, 2)
void grouped_fc_kernel(const float* __restrict__ X,
                       const float* __restrict__ W,
                       const float* __restrict__ Bias,
                       float* __restrict__ Out) {
    // XCD swizzle (bijective: 256 % 8 == 0): XCD j gets batches [8j, 8j+8)
    const int swz  = (blockIdx.x & 7) * 32 + (blockIdx.x >> 3);
    const int bidx = swz >> 2;     // 0..63 batch
    const int tn   = swz & 3;      // 0..3 N-tile

    const int tid  = threadIdx.x;
    const int lane = tid & 63;
    const int wid  = tid >> 6;
    const int wm   = wid & 1;      // 2 wave rows (128 out-rows)
    const int wn   = wid >> 1;     // 4 wave cols (64 out-cols)

    // [row][64] bf16 = 8 x 16B slots/row; slot s at s ^ (row&7).
    // R9/R13/R21-measured: SQ_LDS_BANK_CONFLICT == 0.
    __shared__ unsigned short ldsA[2][BM][BK];
    __shared__ unsigned short ldsB[2][BN][BK];

    const float* srcA0 = X + ((size_t)bidx * MDIM + 0 * BM) * KDIM;
    const float* srcA1 = X + ((size_t)bidx * MDIM + 1 * BM) * KDIM;
    const float* srcB  = W + ((size_t)bidx * NDIM + (size_t)tn * BN) * KDIM;

    // staging: 4 threads/row, 16 fp32 each, per 128-row half-tile
    const int s_r  = tid >> 2;
    const int s_cf = (tid & 3) * 16;
    const int s_x  = s_r & 7;
    const int so0  = (((tid & 3) * 2)     ^ s_x) * 8;
    const int so1  = (((tid & 3) * 2 + 1) ^ s_x) * 8;

    f32x4 st0[4], st1[4];

    auto ISSUE = [&](const float* srcbase, int hv, int kt_, f32x4 (&s)[4]) {
        const float* p = srcbase + (size_t)(hv * 128 + s_r) * KDIM + kt_ * BK + s_cf;
#pragma unroll
        for (int v = 0; v < 4; ++v) s[v] = *(const f32x4*)(p + v * 4);
    };

    auto CVTW = [&](unsigned short* ldsbase, int hv, f32x4 (&s)[4]) {
        const int row = hv * 128 + s_r;
        u32x4 w0, w1;
        w0[0] = cvt2(s[0][0], s[0][1]); w0[1] = cvt2(s[0][2], s[0][3]);
        w0[2] = cvt2(s[1][0], s[1][1]); w0[3] = cvt2(s[1][2], s[1][3]);
        w1[0] = cvt2(s[2][0], s[2][1]); w1[1] = cvt2(s[2][2], s[2][3]);
        w1[2] = cvt2(s[3][0], s[3][1]); w1[3] = cvt2(s[3][2], s[3][3]);
        *(u32x4*)&ldsbase[(size_t)row * BK + so0] = w0;
        *(u32x4*)&ldsbase[(size_t)row * BK + so1] = w1;
    };

    // frag reads: row&7 == frow&7 (frag base rows are multiples of 8)
    const int frow = lane & 15;
    const int khi  = lane >> 4;
    const int xr   = frow & 7;
    const int oK0  = ((khi)     ^ xr) * 8;
    const int oK1  = ((4 + khi) ^ xr) * 8;

    auto rdA = [&](int buf, int mi, int o) {
        return *(const bf16x8*)&ldsA[buf][wm * 128 + mi * 16 + frow][o];
    };
    auto rdB = [&](int buf, int ni, int o) {
        return *(const bf16x8*)&ldsB[buf][wn * 64 + ni * 16 + frow][o];
    };

    f32x4 acc[8][4];
#pragma unroll
    for (int mi = 0; mi < 8; ++mi)
#pragma unroll
        for (int ni = 0; ni < 4; ++ni)
            acc[mi][ni] = (f32x4){0.f, 0.f, 0.f, 0.f};

    // ---- prologue (tm=0): stage tile 0 -> buf0; tile-1 A halves in flight
    ISSUE(srcA0, 0, 0, st0); ISSUE(srcA0, 1, 0, st1);
    CVTW(&ldsA[0][0][0], 0, st0); CVTW(&ldsA[0][0][0], 1, st1);
    ISSUE(srcB, 0, 0, st0); ISSUE(srcB, 1, 0, st1);
    CVTW(&ldsB[0][0][0], 0, st0); CVTW(&ldsB[0][0][0], 1, st1);
    ISSUE(srcA0, 0, 1, st0); ISSUE(srcA0, 1, 1, st1);
    WAITLG(0);
    BAR;

    bf16x8 af[8], bfr[4];

#pragma unroll
    for (int tm = 0; tm < 2; ++tm) {
        const float* srcA = tm ? srcA1 : srcA0;

        // ---- main loop: R21 verbatim, except at kt=NKT-2 the dead m2
        // ISSUE slots pre-issue tile-0 A of the NEXT pair-member (tm==0).
#pragma unroll 1
        for (int kt = 0; kt < NKT - 1; ++kt) {
            const int rd = kt & 1;
            const bool m2 = (kt + 2 < NKT);
            unsigned short* nA = &ldsA[rd ^ 1][0][0];
            unsigned short* nB = &ldsB[rd ^ 1][0][0];

            // ---- P0 ----
#pragma unroll
            for (int mi = 0; mi < 8; ++mi) af[mi] = rdA(rd, mi, oK0);
            bfr[0] = rdB(rd, 0, oK0); bfr[1] = rdB(rd, 1, oK0);
            WAITLG(0);
            __builtin_amdgcn_s_setprio(1);
#pragma unroll
            for (int mi = 0; mi < 8; ++mi) {
                acc[mi][0] = MFMA16(af[mi], bfr[0], acc[mi][0]);
                acc[mi][1] = MFMA16(af[mi], bfr[1], acc[mi][1]);
            }
            __builtin_amdgcn_s_setprio(0);
            bfr[2] = rdB(rd, 2, oK0); bfr[3] = rdB(rd, 3, oK0);
            SB0;
            CVTW(nA, 0, st0);
            ISSUE(srcB, 0, kt + 1, st0);
            BAR;

            // ---- P1 ----
            WAITLG(2);
            __builtin_amdgcn_s_setprio(1);
#pragma unroll
            for (int mi = 0; mi < 8; ++mi) {
                acc[mi][2] = MFMA16(af[mi], bfr[2], acc[mi][2]);
                acc[mi][3] = MFMA16(af[mi], bfr[3], acc[mi][3]);
            }
            __builtin_amdgcn_s_setprio(0);
#pragma unroll
            for (int mi = 0; mi < 8; ++mi) af[mi] = rdA(rd, mi, oK1);
            bfr[0] = rdB(rd, 0, oK1); bfr[1] = rdB(rd, 1, oK1);
            SB0;
            CVTW(nA, 1, st1);
            ISSUE(srcB, 1, kt + 1, st1);
            BAR;

            // ---- P2 ----
            WAITLG(2);
            __builtin_amdgcn_s_setprio(1);
#pragma unroll
            for (int mi = 0; mi < 8; ++mi) {
                acc[mi][0] = MFMA16(af[mi], bfr[0], acc[mi][0]);
                acc[mi][1] = MFMA16(af[mi], bfr[1], acc[mi][1]);
            }
            __builtin_amdgcn_s_setprio(0);
            bfr[2] = rdB(rd, 2, oK1); bfr[3] = rdB(rd, 3, oK1);
            SB0;
            CVTW(nB, 0, st0); CVTW(nB, 1, st1);
            if (m2)           ISSUE(srcA, 0, kt + 2, st0);
            else if (tm == 0) ISSUE(srcA1, 0, 0, st0);   // next pair-member
            BAR;

            // ---- P3 + tile seal ----
            WAITLG(4);
            __builtin_amdgcn_s_setprio(1);
#pragma unroll
            for (int mi = 0; mi < 8; ++mi) {
                acc[mi][2] = MFMA16(af[mi], bfr[2], acc[mi][2]);
                acc[mi][3] = MFMA16(af[mi], bfr[3], acc[mi][3]);
            }
            __builtin_amdgcn_s_setprio(0);
            if (m2)           ISSUE(srcA, 1, kt + 2, st1);
            else if (tm == 0) ISSUE(srcA1, 1, 0, st1);   // next pair-member
            WAITLG(0);
            BAR;
        }

        // ---- peeled last tile (rd = 1) ----
        {
            const int rd = (NKT - 1) & 1;
            // ks0
#pragma unroll
            for (int mi = 0; mi < 8; ++mi) af[mi] = rdA(rd, mi, oK0);
#pragma unroll
            for (int ni = 0; ni < 4; ++ni) bfr[ni] = rdB(rd, ni, oK0);
            WAITLG(0);
            __builtin_amdgcn_s_setprio(1);
#pragma unroll
            for (int mi = 0; mi < 8; ++mi)
#pragma unroll
                for (int ni = 0; ni < 4; ++ni)
                    acc[mi][ni] = MFMA16(af[mi], bfr[ni], acc[mi][ni]);
            __builtin_amdgcn_s_setprio(0);
            SB0;
            // ks1 reads first (12r), then (tm==0) publish A1(t0) -> buf0
#pragma unroll
            for (int mi = 0; mi < 8; ++mi) af[mi] = rdA(rd, mi, oK1);
#pragma unroll
            for (int ni = 0; ni < 4; ++ni) bfr[ni] = rdB(rd, ni, oK1);
            SB0;
            if (tm == 0) {
                // buf0 free since kt=NKT-2's seal; A1(t0) loads issued at
                // kt=NKT-2 P2/P3 (>1 phase of flight).
                CVTW(&ldsA[0][0][0], 0, st0);
                CVTW(&ldsA[0][0][0], 1, st1);              // 4 writes
                WAITLG(4);                                  // 12 reads done
            } else {
                WAITLG(0);
            }
            __builtin_amdgcn_s_setprio(1);
#pragma unroll
            for (int mi = 0; mi < 8; ++mi)
#pragma unroll
                for (int ni = 0; ni < 4; ++ni)
                    acc[mi][ni] = MFMA16(af[mi], bfr[ni], acc[mi][ni]);
            __builtin_amdgcn_s_setprio(0);
            if (tm == 0) {
                // B(t0) re-issue (L2-hot, same tn) and publish -> buf0
                ISSUE(srcB, 0, 0, st0); ISSUE(srcB, 1, 0, st1);
                CVTW(&ldsB[0][0][0], 0, st0);
                CVTW(&ldsB[0][0][0], 1, st1);
            }
        }

        // ---- epilogue for this tm (stores overlap next pair staging) ----
        // acc layout col=lane&15, row=(lane>>4)*4+r (m89-verified)
#pragma unroll
        for (int ni = 0; ni < 4; ++ni) {
            const int gc = tn * BN + wn * 64 + ni * 16 + frow;
            const float bv = Bias[bidx * NDIM + gc];
#pragma unroll
            for (int mi = 0; mi < 8; ++mi) {
                const int gr0 = tm * BM + wm * 128 + mi * 16 + khi * 4;
                float* po = Out + ((size_t)bidx * MDIM + gr0) * NDIM + gc;
#pragma unroll
                for (int r = 0; r < 4; ++r)
                    po[(size_t)r * NDIM] = acc[mi][ni][r] + bv;
            }
        }

        if (tm == 0) {
            // reset acc; pre-issue tile-1 A halves (steady-state entry);
            // seal buf0 for tm=1's readers.
#pragma unroll
            for (int mi = 0; mi < 8; ++mi)
#pragma unroll
                for (int ni = 0; ni < 4; ++ni)
                    acc[mi][ni] = (f32x4){0.f, 0.f, 0.f, 0.f};
            ISSUE(srcA1, 0, 1, st0); ISSUE(srcA1, 1, 1, st1);
            WAITLG(0);      // drain buf0 writes (release edge)
            BAR;            // buf0 sealed; all buf1 reads consumed
        }
    }
}

extern "C" void kernel_launch(void* const* d_in, const int* in_sizes, int n_in,
                              void* d_out, int out_size, void* d_ws, size_t ws_size,
                              hipStream_t stream) {
    const float* X  = (const float*)d_in[0];
    const float* W  = (const float*)d_in[1];
    const float* Bs = (const float*)d_in[2];
    float* Out = (float*)d_out;

    grouped_fc_kernel<<<dim3(256), dim3(512), 0, stream>>>(X, W, Bs, Out);
}

// Round 26
// 155.572 us; speedup vs baseline: 1.2980x; 1.2980x over previous
//
#include <hip/hip_runtime.h>
#include <hip/hip_bf16.h>

#define BATCH 64
#define MDIM 512
#define NDIM 1024
#define KDIM 1024

#define BM 256
#define BN 256
#define BK 64
#define NKT (KDIM / BK)     // 16 K-tiles

typedef __attribute__((ext_vector_type(4))) float f32x4;
typedef __attribute__((ext_vector_type(8))) short bf16x8;
typedef __attribute__((ext_vector_type(4))) unsigned int u32x4;

__device__ __forceinline__ unsigned int cvt2(float lo, float hi) {
    __hip_bfloat162 h = __float22bfloat162_rn(float2{lo, hi});
    return *(unsigned int*)&h;
}

// NOTE operand order: first arg = bfr (W-frag) so the accumulator comes out
// TRANSPOSED: reg axis = W-col, lane&15 = X-row. Input fragment layouts are
// identical for both operands (row=lane&15, k-slot=lane>>4), so the swap is
// semantically exact; only the C/D mapping flips (verified by absmax).
#define MFMA16(a, b, c) __builtin_amdgcn_mfma_f32_16x16x32_bf16((a), (b), (c), 0, 0, 0)
#define SB0 __builtin_amdgcn_sched_barrier(0)
#define WAITLG(n) do { asm volatile("s_waitcnt lgkmcnt(" #n ")" ::: "memory"); SB0; } while (0)
#define BAR do { SB0; __builtin_amdgcn_s_barrier(); SB0; } while (0)

__global__ __launch_bounds__(512, 2)
void grouped_fc_kernel(const float* __restrict__ X,
                       const float* __restrict__ W,
                       const float* __restrict__ Bias,
                       float* __restrict__ Out) {
    // XCD swizzle (bijective: 512 % 8 == 0)
    const int swz  = (blockIdx.x & 7) * 64 + (blockIdx.x >> 3);
    const int bidx = swz >> 3;
    const int tile = swz & 7;
    const int tm = tile & 1;
    const int tn = tile >> 1;

    const int tid  = threadIdx.x;
    const int lane = tid & 63;
    const int wid  = tid >> 6;
    const int wm   = wid & 1;      // 2 wave rows (128 out-rows)
    const int wn   = wid >> 1;     // 4 wave cols (64 out-cols)

    // [row][64] bf16 = 8 x 16B slots/row; slot s at s ^ (row&7).
    // R9/R13/R21-measured: SQ_LDS_BANK_CONFLICT == 0.
    __shared__ unsigned short ldsA[2][BM][BK];
    __shared__ unsigned short ldsB[2][BN][BK];

    const float* srcA = X + ((size_t)bidx * MDIM + (size_t)tm * BM) * KDIM;
    const float* srcB = W + ((size_t)bidx * NDIM + (size_t)tn * BN) * KDIM;

    // staging: 4 threads/row, 16 fp32 each, per 128-row half-tile
    const int s_r  = tid >> 2;
    const int s_cf = (tid & 3) * 16;
    const int s_x  = s_r & 7;
    const int so0  = (((tid & 3) * 2)     ^ s_x) * 8;
    const int so1  = (((tid & 3) * 2 + 1) ^ s_x) * 8;

    f32x4 st0[4], st1[4];

    auto ISSUE = [&](const float* srcbase, int hv, int kt_, f32x4 (&s)[4]) {
        const float* p = srcbase + (size_t)(hv * 128 + s_r) * KDIM + kt_ * BK + s_cf;
#pragma unroll
        for (int v = 0; v < 4; ++v) s[v] = *(const f32x4*)(p + v * 4);
    };

    auto CVTW = [&](unsigned short* ldsbase, int hv, f32x4 (&s)[4]) {
        const int row = hv * 128 + s_r;
        u32x4 w0, w1;
        w0[0] = cvt2(s[0][0], s[0][1]); w0[1] = cvt2(s[0][2], s[0][3]);
        w0[2] = cvt2(s[1][0], s[1][1]); w0[3] = cvt2(s[1][2], s[1][3]);
        w1[0] = cvt2(s[2][0], s[2][1]); w1[1] = cvt2(s[2][2], s[2][3]);
        w1[2] = cvt2(s[3][0], s[3][1]); w1[3] = cvt2(s[3][2], s[3][3]);
        *(u32x4*)&ldsbase[(size_t)row * BK + so0] = w0;
        *(u32x4*)&ldsbase[(size_t)row * BK + so1] = w1;
    };

    // frag reads: row&7 == frow&7 (frag base rows are multiples of 8)
    const int frow = lane & 15;
    const int khi  = lane >> 4;
    const int xr   = frow & 7;
    const int oK0  = ((khi)     ^ xr) * 8;
    const int oK1  = ((4 + khi) ^ xr) * 8;

    auto rdA = [&](int buf, int mi, int o) {
        return *(const bf16x8*)&ldsA[buf][wm * 128 + mi * 16 + frow][o];
    };
    auto rdB = [&](int buf, int ni, int o) {
        return *(const bf16x8*)&ldsB[buf][wn * 64 + ni * 16 + frow][o];
    };

    f32x4 acc[8][4];
#pragma unroll
    for (int mi = 0; mi < 8; ++mi)
#pragma unroll
        for (int ni = 0; ni < 4; ++ni)
            acc[mi][ni] = (f32x4){0.f, 0.f, 0.f, 0.f};

    // ---- prologue: stage tile 0 -> buf0; issue tile-1 A halves ----
    ISSUE(srcA, 0, 0, st0); ISSUE(srcA, 1, 0, st1);
    CVTW(&ldsA[0][0][0], 0, st0); CVTW(&ldsA[0][0][0], 1, st1);
    ISSUE(srcB, 0, 0, st0); ISSUE(srcB, 1, 0, st1);
    CVTW(&ldsB[0][0][0], 0, st0); CVTW(&ldsB[0][0][0], 1, st1);
    ISSUE(srcA, 0, 1, st0); ISSUE(srcA, 1, 1, st1);
    WAITLG(0);
    BAR;

    bf16x8 af[8], bfr[4];

    // main loop: R21 verbatim (counted lgkm waits, 4 phases/tile, one
    // barrier each) with swapped MFMA operand order (transposed acc).
#pragma unroll 1
    for (int kt = 0; kt < NKT - 1; ++kt) {
        const int rd = kt & 1;
        const bool m2 = (kt + 2 < NKT);
        unsigned short* nA = &ldsA[rd ^ 1][0][0];
        unsigned short* nB = &ldsB[rd ^ 1][0][0];

        // ---- P0 ----
#pragma unroll
        for (int mi = 0; mi < 8; ++mi) af[mi] = rdA(rd, mi, oK0);
        bfr[0] = rdB(rd, 0, oK0); bfr[1] = rdB(rd, 1, oK0);
        WAITLG(0);
        __builtin_amdgcn_s_setprio(1);
#pragma unroll
        for (int mi = 0; mi < 8; ++mi) {
            acc[mi][0] = MFMA16(bfr[0], af[mi], acc[mi][0]);
            acc[mi][1] = MFMA16(bfr[1], af[mi], acc[mi][1]);
        }
        __builtin_amdgcn_s_setprio(0);
        bfr[2] = rdB(rd, 2, oK0); bfr[3] = rdB(rd, 3, oK0);
        SB0;
        CVTW(nA, 0, st0);
        ISSUE(srcB, 0, kt + 1, st0);
        BAR;

        // ---- P1 ----
        WAITLG(2);
        __builtin_amdgcn_s_setprio(1);
#pragma unroll
        for (int mi = 0; mi < 8; ++mi) {
            acc[mi][2] = MFMA16(bfr[2], af[mi], acc[mi][2]);
            acc[mi][3] = MFMA16(bfr[3], af[mi], acc[mi][3]);
        }
        __builtin_amdgcn_s_setprio(0);
#pragma unroll
        for (int mi = 0; mi < 8; ++mi) af[mi] = rdA(rd, mi, oK1);
        bfr[0] = rdB(rd, 0, oK1); bfr[1] = rdB(rd, 1, oK1);
        SB0;
        CVTW(nA, 1, st1);
        ISSUE(srcB, 1, kt + 1, st1);
        BAR;

        // ---- P2 ----
        WAITLG(2);
        __builtin_amdgcn_s_setprio(1);
#pragma unroll
        for (int mi = 0; mi < 8; ++mi) {
            acc[mi][0] = MFMA16(bfr[0], af[mi], acc[mi][0]);
            acc[mi][1] = MFMA16(bfr[1], af[mi], acc[mi][1]);
        }
        __builtin_amdgcn_s_setprio(0);
        bfr[2] = rdB(rd, 2, oK1); bfr[3] = rdB(rd, 3, oK1);
        SB0;
        CVTW(nB, 0, st0); CVTW(nB, 1, st1);
        if (m2) ISSUE(srcA, 0, kt + 2, st0);
        BAR;

        // ---- P3 + tile seal ----
        WAITLG(4);
        __builtin_amdgcn_s_setprio(1);
#pragma unroll
        for (int mi = 0; mi < 8; ++mi) {
            acc[mi][2] = MFMA16(bfr[2], af[mi], acc[mi][2]);
            acc[mi][3] = MFMA16(bfr[3], af[mi], acc[mi][3]);
        }
        __builtin_amdgcn_s_setprio(0);
        if (m2) ISSUE(srcA, 1, kt + 2, st1);
        WAITLG(0);
        BAR;
    }

    // ---- peeled last tile (no staging) ----
    {
        const int rd = (NKT - 1) & 1;
#pragma unroll
        for (int mi = 0; mi < 8; ++mi) af[mi] = rdA(rd, mi, oK0);
#pragma unroll
        for (int ni = 0; ni < 4; ++ni) bfr[ni] = rdB(rd, ni, oK0);
        WAITLG(0);
#pragma unroll
        for (int mi = 0; mi < 8; ++mi)
#pragma unroll
            for (int ni = 0; ni < 4; ++ni)
                acc[mi][ni] = MFMA16(bfr[ni], af[mi], acc[mi][ni]);
#pragma unroll
        for (int mi = 0; mi < 8; ++mi) af[mi] = rdA(rd, mi, oK1);
#pragma unroll
        for (int ni = 0; ni < 4; ++ni) bfr[ni] = rdB(rd, ni, oK1);
        WAITLG(0);
#pragma unroll
        for (int mi = 0; mi < 8; ++mi)
#pragma unroll
            for (int ni = 0; ni < 4; ++ni)
                acc[mi][ni] = MFMA16(bfr[ni], af[mi], acc[mi][ni]);
    }

    // epilogue (transposed acc): reg axis = W-col -> each lane holds 4
    // CONSECUTIVE output cols of one row = one contiguous f32x4 store.
    // col = tn*BN + wn*64 + ni*16 + khi*4 + r ; row = tm*BM + wm*128 +
    // mi*16 + frow. 32 dwordx4 stores/thread (was 128 dword stores).
#pragma unroll
    for (int ni = 0; ni < 4; ++ni) {
        const int gcb = tn * BN + wn * 64 + ni * 16 + khi * 4;
        const f32x4 bv4 = *(const f32x4*)&Bias[(size_t)bidx * NDIM + gcb];
#pragma unroll
        for (int mi = 0; mi < 8; ++mi) {
            const int gr = tm * BM + wm * 128 + mi * 16 + frow;
            float* po = Out + ((size_t)bidx * MDIM + gr) * NDIM + gcb;
            *(f32x4*)po = acc[mi][ni] + bv4;
        }
    }
}

extern "C" void kernel_launch(void* const* d_in, const int* in_sizes, int n_in,
                              void* d_out, int out_size, void* d_ws, size_t ws_size,
                              hipStream_t stream) {
    const float* X  = (const float*)d_in[0];
    const float* W  = (const float*)d_in[1];
    const float* Bs = (const float*)d_in[2];
    float* Out = (float*)d_out;

    grouped_fc_kernel<<<dim3(512), dim3(512), 0, stream>>>(X, W, Bs, Out);
}

// Round 27
// 144.104 us; speedup vs baseline: 1.4013x; 1.0796x over previous
//
#include <hip/hip_runtime.h>
#include <hip/hip_bf16.h>

#define BATCH 64
#define MDIM 512
#define NDIM 1024
#define KDIM 1024

#define BM 256
#define BN 256
#define BK 64
#define NKT (KDIM / BK)     // 16 K-tiles

typedef __attribute__((ext_vector_type(4))) float f32x4;
typedef __attribute__((ext_vector_type(8))) short bf16x8;
typedef __attribute__((ext_vector_type(4))) unsigned int u32x4;

__device__ __forceinline__ unsigned int cvt2(float lo, float hi) {
    __hip_bfloat162 h = __float22bfloat162_rn(float2{lo, hi});
    return *(unsigned int*)&h;
}

#define MFMA16(a, b, c) __builtin_amdgcn_mfma_f32_16x16x32_bf16((a), (b), (c), 0, 0, 0)
#define SB0 __builtin_amdgcn_sched_barrier(0)
// counted lgkm wait; SB0 after is rule-18 correctness (hipcc hoists
// register-only MFMA past inline-asm waitcnt otherwise).
#define WAITLG(n) do { asm volatile("s_waitcnt lgkmcnt(" #n ")" ::: "memory"); SB0; } while (0)
#define BAR do { SB0; __builtin_amdgcn_s_barrier(); SB0; } while (0)

__global__ __launch_bounds__(512, 2)
void grouped_fc_kernel(const float* __restrict__ X,
                       const float* __restrict__ W,
                       const float* __restrict__ Bias,
                       float* __restrict__ Out) {
    // XCD swizzle (bijective: 512 % 8 == 0)
    const int swz  = (blockIdx.x & 7) * 64 + (blockIdx.x >> 3);
    const int bidx = swz >> 3;
    const int tile = swz & 7;
    const int tm = tile & 1;
    const int tn = tile >> 1;

    const int tid  = threadIdx.x;
    const int lane = tid & 63;
    const int wid  = tid >> 6;
    const int wm   = wid & 1;      // 2 wave rows (128 out-rows)
    const int wn   = wid >> 1;     // 4 wave cols (64 out-cols)

    // [row][64] bf16 = 8 x 16B slots/row; slot s at s ^ (row&7).
    // R9/R13/R21-measured: SQ_LDS_BANK_CONFLICT == 0.
    __shared__ unsigned short ldsA[2][BM][BK];
    __shared__ unsigned short ldsB[2][BN][BK];

    const float* srcA = X + ((size_t)bidx * MDIM + (size_t)tm * BM) * KDIM;
    const float* srcB = W + ((size_t)bidx * NDIM + (size_t)tn * BN) * KDIM;

    // staging: 4 threads/row, 16 fp32 each, per 128-row half-tile
    const int s_r  = tid >> 2;
    const int s_cf = (tid & 3) * 16;
    const int s_x  = s_r & 7;
    const int so0  = (((tid & 3) * 2)     ^ s_x) * 8;
    const int so1  = (((tid & 3) * 2 + 1) ^ s_x) * 8;

    f32x4 st0[4], st1[4];

    auto ISSUE = [&](const float* srcbase, int hv, int kt_, f32x4 (&s)[4]) {
        const float* p = srcbase + (size_t)(hv * 128 + s_r) * KDIM + kt_ * BK + s_cf;
#pragma unroll
        for (int v = 0; v < 4; ++v) s[v] = *(const f32x4*)(p + v * 4);
    };

    auto CVTW = [&](unsigned short* ldsbase, int hv, f32x4 (&s)[4]) {
        const int row = hv * 128 + s_r;
        u32x4 w0, w1;
        w0[0] = cvt2(s[0][0], s[0][1]); w0[1] = cvt2(s[0][2], s[0][3]);
        w0[2] = cvt2(s[1][0], s[1][1]); w0[3] = cvt2(s[1][2], s[1][3]);
        w1[0] = cvt2(s[2][0], s[2][1]); w1[1] = cvt2(s[2][2], s[2][3]);
        w1[2] = cvt2(s[3][0], s[3][1]); w1[3] = cvt2(s[3][2], s[3][3]);
        *(u32x4*)&ldsbase[(size_t)row * BK + so0] = w0;
        *(u32x4*)&ldsbase[(size_t)row * BK + so1] = w1;
    };

    // frag reads: row&7 == frow&7 (frag base rows are multiples of 8)
    const int frow = lane & 15;
    const int khi  = lane >> 4;
    const int xr   = frow & 7;
    const int oK0  = ((khi)     ^ xr) * 8;
    const int oK1  = ((4 + khi) ^ xr) * 8;

    auto rdA = [&](int buf, int mi, int o) {
        return *(const bf16x8*)&ldsA[buf][wm * 128 + mi * 16 + frow][o];
    };
    auto rdB = [&](int buf, int ni, int o) {
        return *(const bf16x8*)&ldsB[buf][wn * 64 + ni * 16 + frow][o];
    };

    f32x4 acc[8][4];
#pragma unroll
    for (int mi = 0; mi < 8; ++mi)
#pragma unroll
        for (int ni = 0; ni < 4; ++ni)
            acc[mi][ni] = (f32x4){0.f, 0.f, 0.f, 0.f};

    // ---- prologue: stage tile 0 -> buf0; issue tile-1 A halves ----
    ISSUE(srcA, 0, 0, st0); ISSUE(srcA, 1, 0, st1);
    CVTW(&ldsA[0][0][0], 0, st0); CVTW(&ldsA[0][0][0], 1, st1);
    ISSUE(srcB, 0, 0, st0); ISSUE(srcB, 1, 0, st1);
    CVTW(&ldsB[0][0][0], 0, st0); CVTW(&ldsB[0][0][0], 1, st1);
    ISSUE(srcA, 0, 1, st0); ISSUE(srcA, 1, 1, st1);
    WAITLG(0);
    BAR;

    bf16x8 af[8], bfr[4];

    // main loop: tiles 0..NKT-2, 4 phases/tile, one barrier each.
    // MFMA clusters may interleave with the following read burst (no fence
    // between them); one SB0 pins reads-before-writes so counted waits are
    // exact. All B-writes consolidated in P2 -> P3 is write-free and the
    // tile-seal drain has a full phase of slack.
#pragma unroll 1
    for (int kt = 0; kt < NKT - 1; ++kt) {
        const int rd = kt & 1;
        const bool m2 = (kt + 2 < NKT);
        unsigned short* nA = &ldsA[rd ^ 1][0][0];
        unsigned short* nB = &ldsB[rd ^ 1][0][0];

        // ---- P0: [10r] wait0 | MFMA{0,1} || 2r ; SB0 ; 2w + ISSUE ----
#pragma unroll
        for (int mi = 0; mi < 8; ++mi) af[mi] = rdA(rd, mi, oK0);
        bfr[0] = rdB(rd, 0, oK0); bfr[1] = rdB(rd, 1, oK0);
        WAITLG(0);
        __builtin_amdgcn_s_setprio(1);
#pragma unroll
        for (int mi = 0; mi < 8; ++mi) {
            acc[mi][0] = MFMA16(af[mi], bfr[0], acc[mi][0]);
            acc[mi][1] = MFMA16(af[mi], bfr[1], acc[mi][1]);
        }
        __builtin_amdgcn_s_setprio(0);
        bfr[2] = rdB(rd, 2, oK0); bfr[3] = rdB(rd, 3, oK0);   // 2 reads
        SB0;                                                   // r-before-w
        CVTW(nA, 0, st0);                                      // 2 writes
        ISSUE(srcB, 0, kt + 1, st0);
        BAR;

        // ---- P1: queue [2r,2w] wait2 | MFMA{2,3} || 10r ; SB0 ; 2w ----
        WAITLG(2);
        __builtin_amdgcn_s_setprio(1);
#pragma unroll
        for (int mi = 0; mi < 8; ++mi) {
            acc[mi][2] = MFMA16(af[mi], bfr[2], acc[mi][2]);
            acc[mi][3] = MFMA16(af[mi], bfr[3], acc[mi][3]);
        }
        __builtin_amdgcn_s_setprio(0);
#pragma unroll
        for (int mi = 0; mi < 8; ++mi) af[mi] = rdA(rd, mi, oK1);  // 8 reads
        bfr[0] = rdB(rd, 0, oK1); bfr[1] = rdB(rd, 1, oK1);        // 2 reads
        SB0;
        CVTW(nA, 1, st1);                                          // 2 writes
        ISSUE(srcB, 1, kt + 1, st1);
        BAR;

        // ---- P2: queue [2w,10r,2w] wait2 | MFMA{0,1} || 2r ; SB0 ; 4w ----
        WAITLG(2);
        __builtin_amdgcn_s_setprio(1);
#pragma unroll
        for (int mi = 0; mi < 8; ++mi) {
            acc[mi][0] = MFMA16(af[mi], bfr[0], acc[mi][0]);
            acc[mi][1] = MFMA16(af[mi], bfr[1], acc[mi][1]);
        }
        __builtin_amdgcn_s_setprio(0);
        bfr[2] = rdB(rd, 2, oK1); bfr[3] = rdB(rd, 3, oK1);   // 2 reads
        SB0;
        CVTW(nB, 0, st0); CVTW(nB, 1, st1);                    // 4 writes
        if (m2) ISSUE(srcA, 0, kt + 2, st0);
        BAR;

        // ---- P3: queue [2w,2r,4w] wait4 | MFMA{2,3} ; seal (1-phase slack) ----
        WAITLG(4);
        __builtin_amdgcn_s_setprio(1);
#pragma unroll
        for (int mi = 0; mi < 8; ++mi) {
            acc[mi][2] = MFMA16(af[mi], bfr[2], acc[mi][2]);
            acc[mi][3] = MFMA16(af[mi], bfr[3], acc[mi][3]);
        }
        __builtin_amdgcn_s_setprio(0);
        if (m2) ISSUE(srcA, 1, kt + 2, st1);
        WAITLG(0);                       // drains P2's writes (~1 phase old)
        BAR;                             // buf^1 sealed
    }

    // ---- peeled last tile (no staging) ----
    {
        const int rd = (NKT - 1) & 1;
#pragma unroll
        for (int mi = 0; mi < 8; ++mi) af[mi] = rdA(rd, mi, oK0);
#pragma unroll
        for (int ni = 0; ni < 4; ++ni) bfr[ni] = rdB(rd, ni, oK0);
        WAITLG(0);
#pragma unroll
        for (int mi = 0; mi < 8; ++mi)
#pragma unroll
            for (int ni = 0; ni < 4; ++ni)
                acc[mi][ni] = MFMA16(af[mi], bfr[ni], acc[mi][ni]);
#pragma unroll
        for (int mi = 0; mi < 8; ++mi) af[mi] = rdA(rd, mi, oK1);
#pragma unroll
        for (int ni = 0; ni < 4; ++ni) bfr[ni] = rdB(rd, ni, oK1);
        WAITLG(0);
#pragma unroll
        for (int mi = 0; mi < 8; ++mi)
#pragma unroll
            for (int ni = 0; ni < 4; ++ni)
                acc[mi][ni] = MFMA16(af[mi], bfr[ni], acc[mi][ni]);
    }

    // epilogue: acc layout col=lane&15, row=(lane>>4)*4+r (m89-verified)
#pragma unroll
    for (int ni = 0; ni < 4; ++ni) {
        const int gc = tn * BN + wn * 64 + ni * 16 + frow;
        const float bv = Bias[bidx * NDIM + gc];
#pragma unroll
        for (int mi = 0; mi < 8; ++mi) {
            const int gr0 = tm * BM + wm * 128 + mi * 16 + khi * 4;
            float* po = Out + ((size_t)bidx * MDIM + gr0) * NDIM + gc;
#pragma unroll
            for (int r = 0; r < 4; ++r)
                po[(size_t)r * NDIM] = acc[mi][ni][r] + bv;
        }
    }
}

extern "C" void kernel_launch(void* const* d_in, const int* in_sizes, int n_in,
                              void* d_out, int out_size, void* d_ws, size_t ws_size,
                              hipStream_t stream) {
    const float* X  = (const float*)d_in[0];
    const float* W  = (const float*)d_in[1];
    const float* Bs = (const float*)d_in[2];
    float* Out = (float*)d_out;

    grouped_fc_kernel<<<dim3(512), dim3(512), 0, stream>>>(X, W, Bs, Out);
}

// Round 28
// 137.502 us; speedup vs baseline: 1.4686x; 1.0480x over previous
//
#include <hip/hip_runtime.h>
#include <hip/hip_bf16.h>

#define BATCH 64
#define MDIM 512
#define NDIM 1024
#define KDIM 1024

#define BM 256
#define BN 256
#define BK 64
#define NKT (KDIM / BK)     // 16 K-tiles

typedef __attribute__((ext_vector_type(4))) float f32x4;
typedef __attribute__((ext_vector_type(8))) short bf16x8;
typedef __attribute__((ext_vector_type(4))) unsigned int u32x4;

__device__ __forceinline__ unsigned int cvt2(float lo, float hi) {
    __hip_bfloat162 h = __float22bfloat162_rn(float2{lo, hi});
    return *(unsigned int*)&h;
}

#define MFMA16(a, b, c) __builtin_amdgcn_mfma_f32_16x16x32_bf16((a), (b), (c), 0, 0, 0)
#define SB0 __builtin_amdgcn_sched_barrier(0)
// counted lgkm wait; SB0 after is rule-18 correctness (hipcc hoists
// register-only MFMA past inline-asm waitcnt otherwise).
#define WAITLG(n) do { asm volatile("s_waitcnt lgkmcnt(" #n ")" ::: "memory"); SB0; } while (0)
#define BAR do { SB0; __builtin_amdgcn_s_barrier(); SB0; } while (0)

__global__ __launch_bounds__(512, 2)
void grouped_fc_kernel(const float* __restrict__ X,
                       const float* __restrict__ W,
                       const float* __restrict__ Bias,
                       float* __restrict__ Out) {
    // XCD swizzle (bijective: 512 % 8 == 0)
    const int swz  = (blockIdx.x & 7) * 64 + (blockIdx.x >> 3);
    const int bidx = swz >> 3;
    const int tile = swz & 7;
    const int tm = tile & 1;
    const int tn = tile >> 1;

    const int tid  = threadIdx.x;
    const int lane = tid & 63;
    const int wid  = tid >> 6;
    const int wm   = wid & 1;      // 2 wave rows (128 out-rows)
    const int wn   = wid >> 1;     // 4 wave cols (64 out-cols)

    // [row][64] bf16 = 8 x 16B slots/row; slot s at s ^ (row&7).
    // R9/R13/R21-measured: SQ_LDS_BANK_CONFLICT == 0.
    __shared__ unsigned short ldsA[2][BM][BK];
    __shared__ unsigned short ldsB[2][BN][BK];

    const float* srcA = X + ((size_t)bidx * MDIM + (size_t)tm * BM) * KDIM;
    const float* srcB = W + ((size_t)bidx * NDIM + (size_t)tn * BN) * KDIM;

    // staging: 4 threads/row, 16 fp32 each, per 128-row half-tile
    const int s_r  = tid >> 2;
    const int s_cf = (tid & 3) * 16;
    const int s_x  = s_r & 7;
    const int so0  = (((tid & 3) * 2)     ^ s_x) * 8;
    const int so1  = (((tid & 3) * 2 + 1) ^ s_x) * 8;

    f32x4 st0[4], st1[4];

    auto ISSUE = [&](const float* srcbase, int hv, int kt_, f32x4 (&s)[4]) {
        const float* p = srcbase + (size_t)(hv * 128 + s_r) * KDIM + kt_ * BK + s_cf;
#pragma unroll
        for (int v = 0; v < 4; ++v) s[v] = *(const f32x4*)(p + v * 4);
    };

    auto CVTW = [&](unsigned short* ldsbase, int hv, f32x4 (&s)[4]) {
        const int row = hv * 128 + s_r;
        u32x4 w0, w1;
        w0[0] = cvt2(s[0][0], s[0][1]); w0[1] = cvt2(s[0][2], s[0][3]);
        w0[2] = cvt2(s[1][0], s[1][1]); w0[3] = cvt2(s[1][2], s[1][3]);
        w1[0] = cvt2(s[2][0], s[2][1]); w1[1] = cvt2(s[2][2], s[2][3]);
        w1[2] = cvt2(s[3][0], s[3][1]); w1[3] = cvt2(s[3][2], s[3][3]);
        *(u32x4*)&ldsbase[(size_t)row * BK + so0] = w0;
        *(u32x4*)&ldsbase[(size_t)row * BK + so1] = w1;
    };

    // frag reads: row&7 == frow&7 (frag base rows are multiples of 8)
    const int frow = lane & 15;
    const int khi  = lane >> 4;
    const int xr   = frow & 7;
    const int oK0  = ((khi)     ^ xr) * 8;
    const int oK1  = ((4 + khi) ^ xr) * 8;

    auto rdA = [&](int buf, int mi, int o) {
        return *(const bf16x8*)&ldsA[buf][wm * 128 + mi * 16 + frow][o];
    };
    auto rdB = [&](int buf, int ni, int o) {
        return *(const bf16x8*)&ldsB[buf][wn * 64 + ni * 16 + frow][o];
    };

    f32x4 acc[8][4];
#pragma unroll
    for (int mi = 0; mi < 8; ++mi)
#pragma unroll
        for (int ni = 0; ni < 4; ++ni)
            acc[mi][ni] = (f32x4){0.f, 0.f, 0.f, 0.f};

    // ---- prologue: stage tile 0 -> buf0; issue tile-1 A halves ----
    ISSUE(srcA, 0, 0, st0); ISSUE(srcA, 1, 0, st1);
    CVTW(&ldsA[0][0][0], 0, st0); CVTW(&ldsA[0][0][0], 1, st1);
    ISSUE(srcB, 0, 0, st0); ISSUE(srcB, 1, 0, st1);
    CVTW(&ldsB[0][0][0], 0, st0); CVTW(&ldsB[0][0][0], 1, st1);
    ISSUE(srcA, 0, 1, st0); ISSUE(srcA, 1, 1, st1);
    WAITLG(0);
    BAR;

    bf16x8 af[8], bfr[4];

    // main loop: tiles 0..NKT-2, 4 phases/tile, one barrier each.
    // Counted lgkm waits leave only the newest ds_writes pending; one SB0
    // pins reads-before-writes so the counts are exact; B-writes
    // consolidated in P2 so the tile-seal drain has a phase of slack.
#pragma unroll 1
    for (int kt = 0; kt < NKT - 1; ++kt) {
        const int rd = kt & 1;
        const bool m2 = (kt + 2 < NKT);
        unsigned short* nA = &ldsA[rd ^ 1][0][0];
        unsigned short* nB = &ldsB[rd ^ 1][0][0];

        // ---- P0: [10r] wait0 | MFMA{0,1} || 2r ; SB0 ; 2w + ISSUE ----
#pragma unroll
        for (int mi = 0; mi < 8; ++mi) af[mi] = rdA(rd, mi, oK0);
        bfr[0] = rdB(rd, 0, oK0); bfr[1] = rdB(rd, 1, oK0);
        WAITLG(0);
        __builtin_amdgcn_s_setprio(1);
#pragma unroll
        for (int mi = 0; mi < 8; ++mi) {
            acc[mi][0] = MFMA16(af[mi], bfr[0], acc[mi][0]);
            acc[mi][1] = MFMA16(af[mi], bfr[1], acc[mi][1]);
        }
        __builtin_amdgcn_s_setprio(0);
        bfr[2] = rdB(rd, 2, oK0); bfr[3] = rdB(rd, 3, oK0);   // 2 reads
        SB0;                                                   // r-before-w
        CVTW(nA, 0, st0);                                      // 2 writes
        ISSUE(srcB, 0, kt + 1, st0);
        BAR;

        // ---- P1: queue [2r,2w] wait2 | MFMA{2,3} || 10r ; SB0 ; 2w ----
        WAITLG(2);
        __builtin_amdgcn_s_setprio(1);
#pragma unroll
        for (int mi = 0; mi < 8; ++mi) {
            acc[mi][2] = MFMA16(af[mi], bfr[2], acc[mi][2]);
            acc[mi][3] = MFMA16(af[mi], bfr[3], acc[mi][3]);
        }
        __builtin_amdgcn_s_setprio(0);
#pragma unroll
        for (int mi = 0; mi < 8; ++mi) af[mi] = rdA(rd, mi, oK1);  // 8 reads
        bfr[0] = rdB(rd, 0, oK1); bfr[1] = rdB(rd, 1, oK1);        // 2 reads
        SB0;
        CVTW(nA, 1, st1);                                          // 2 writes
        ISSUE(srcB, 1, kt + 1, st1);
        BAR;

        // ---- P2: queue [2w,10r,2w] wait2 | MFMA{0,1} || 2r ; SB0 ; 4w ----
        WAITLG(2);
        __builtin_amdgcn_s_setprio(1);
#pragma unroll
        for (int mi = 0; mi < 8; ++mi) {
            acc[mi][0] = MFMA16(af[mi], bfr[0], acc[mi][0]);
            acc[mi][1] = MFMA16(af[mi], bfr[1], acc[mi][1]);
        }
        __builtin_amdgcn_s_setprio(0);
        bfr[2] = rdB(rd, 2, oK1); bfr[3] = rdB(rd, 3, oK1);   // 2 reads
        SB0;
        CVTW(nB, 0, st0); CVTW(nB, 1, st1);                    // 4 writes
        if (m2) ISSUE(srcA, 0, kt + 2, st0);
        BAR;

        // ---- P3: queue [2w,2r,4w] wait4 | MFMA{2,3} ; seal ----
        WAITLG(4);
        __builtin_amdgcn_s_setprio(1);
#pragma unroll
        for (int mi = 0; mi < 8; ++mi) {
            acc[mi][2] = MFMA16(af[mi], bfr[2], acc[mi][2]);
            acc[mi][3] = MFMA16(af[mi], bfr[3], acc[mi][3]);
        }
        __builtin_amdgcn_s_setprio(0);
        if (m2) ISSUE(srcA, 1, kt + 2, st1);
        WAITLG(0);                       // drains P2's writes (~1 phase old)
        BAR;                             // buf^1 sealed
    }

    // ---- peeled last tile (no staging) ----
    {
        const int rd = (NKT - 1) & 1;
#pragma unroll
        for (int mi = 0; mi < 8; ++mi) af[mi] = rdA(rd, mi, oK0);
#pragma unroll
        for (int ni = 0; ni < 4; ++ni) bfr[ni] = rdB(rd, ni, oK0);
        WAITLG(0);
#pragma unroll
        for (int mi = 0; mi < 8; ++mi)
#pragma unroll
            for (int ni = 0; ni < 4; ++ni)
                acc[mi][ni] = MFMA16(af[mi], bfr[ni], acc[mi][ni]);
#pragma unroll
        for (int mi = 0; mi < 8; ++mi) af[mi] = rdA(rd, mi, oK1);
#pragma unroll
        for (int ni = 0; ni < 4; ++ni) bfr[ni] = rdB(rd, ni, oK1);
        WAITLG(0);
#pragma unroll
        for (int mi = 0; mi < 8; ++mi)
#pragma unroll
            for (int ni = 0; ni < 4; ++ni)
                acc[mi][ni] = MFMA16(af[mi], bfr[ni], acc[mi][ni]);
    }

    // epilogue: acc layout col=lane&15, row=(lane>>4)*4+r (m89-verified)
#pragma unroll
    for (int ni = 0; ni < 4; ++ni) {
        const int gc = tn * BN + wn * 64 + ni * 16 + frow;
        const float bv = Bias[bidx * NDIM + gc];
#pragma unroll
        for (int mi = 0; mi < 8; ++mi) {
            const int gr0 = tm * BM + wm * 128 + mi * 16 + khi * 4;
            float* po = Out + ((size_t)bidx * MDIM + gr0) * NDIM + gc;
#pragma unroll
            for (int r = 0; r < 4; ++r)
                po[(size_t)r * NDIM] = acc[mi][ni][r] + bv;
        }
    }
}

extern "C" void kernel_launch(void* const* d_in, const int* in_sizes, int n_in,
                              void* d_out, int out_size, void* d_ws, size_t ws_size,
                              hipStream_t stream) {
    const float* X  = (const float*)d_in[0];
    const float* W  = (const float*)d_in[1];
    const float* Bs = (const float*)d_in[2];
    float* Out = (float*)d_out;

    grouped_fc_kernel<<<dim3(512), dim3(512), 0, stream>>>(X, W, Bs, Out);
}